// Round 5
// baseline (413.144 us; speedup 1.0000x reference)
//
#include <hip/hip_runtime.h>

// SpikeLoss: loss = 0.5 * sum((outputs - psp(target))^2)
// psp: syn_t = syn_{t-1}*decay + x_t ; psp_t = syn_t/tau, decay = 1 - 1/tau.
//
// R5: full-lane coalesced segmented-scan streaming.
//  - each wave owns 64 CONSECUTIVE pixels = 1600 float4 chunks; 25 iterations
//    of 64 chunks (1 KB per array per load instr, all 64 lanes useful)
//  - pixel boundaries fall mid-window: segmented Kogge-Stone with per-lane
//    in-pixel chunk position j = (j0 + lane) mod 25; KS step d masked by
//    (j>=d && lane>=d)  [first partial segment gets full in-window prefix,
//    later segments reset at j==0]
//  - the window's leading partial pixel gets its pre-window history from a
//    register `carry` (syn at end of previous window), injected into
//    first-segment lanes as carry * decay^(4*lane); carry refreshed per
//    iteration via one broadcast shuffle from lane 63
//  - next iteration's loads issued before processing current (2 extra float4
//    in flight); 32 waves/CU via __launch_bounds__(256, 8)

constexpr int T     = 100;  // trailing axis length
constexpr int C4    = 25;   // float4 chunks per pixel
constexpr int PPW   = 64;   // pixels per wave
constexpr int CPW   = C4 * PPW;   // 1600 chunks per wave
constexpr int ITERS = CPW / 64;   // 25 windows of 64 chunks

__global__ __launch_bounds__(256, 8) void spike_loss_kernel(
    const float4* __restrict__ tgt4,
    const float4* __restrict__ outs4,
    const int*    __restrict__ tau_p,
    float*        __restrict__ out)    // [1], pre-zeroed
{
    const float tau     = (float)tau_p[0];
    const float inv_tau = 1.0f / tau;
    const float dd1     = 1.0f - inv_tau;      // decay
    const float dd2 = dd1 * dd1;
    const float dd3 = dd2 * dd1;
    const float dd4 = dd2 * dd2;
    const float a1 = dd4;                      // per-chunk carry factor
    const float a2 = a1 * a1;
    const float a4 = a2 * a2;
    const float a8 = a4 * a4;

    const int lane    = threadIdx.x & 63;
    const int wave_id = (blockIdx.x * blockDim.x + threadIdx.x) >> 6;

    // decay^(4*lane): first-partial-segment carry weight (one-time cost;
    // only lanes < 25 ever use it, underflow beyond is harmless)
    const float pw = __builtin_exp2f(4.0f * (float)lane * __builtin_log2f(dd1));

    const float4* tp = tgt4  + (size_t)wave_id * CPW + lane;
    const float4* op = outs4 + (size_t)wave_id * CPW + lane;

    float acc   = 0.0f;
    float carry = 0.0f;
    int   j0    = 0;     // in-pixel chunk position of window's first chunk

    float4 tc = tp[0];
    float4 oc = op[0];

    for (int it = 0; it < ITERS; ++it) {
        // prefetch next window (clamped reload on last iter — harmless)
        const int nxt = (it + 1 < ITERS ? it + 1 : it) * 64;
        const float4 tn = tp[nxt];
        const float4 on = op[nxt];

        // per-lane in-pixel chunk position
        int j = j0 + lane;              // <= 24 + 63 = 87
        if (j >= 50) j -= 50;
        if (j >= 25) j -= 25;

        // local inclusive scan over the 4 elements (zero carry-in)
        const float s0 = tc.x;
        const float s1 = fmaf(s0, dd1, tc.y);
        const float s2 = fmaf(s1, dd1, tc.z);
        const float s3 = fmaf(s2, dd1, tc.w);

        // segmented Kogge-Stone over chunk-end values
        float X = s3, y;
        y = __shfl_up(X, 1, 64); if (j >= 1 && lane >= 1) X = fmaf(y, a1, X);
        y = __shfl_up(X, 2, 64); if (j >= 2 && lane >= 2) X = fmaf(y, a2, X);
        y = __shfl_up(X, 4, 64); if (j >= 4 && lane >= 4) X = fmaf(y, a4, X);
        y = __shfl_up(X, 8, 64); if (j >= 8 && lane >= 8) X = fmaf(y, a8, X);

        // carry-in for this chunk (syn at end of previous chunk)
        const float cinw  = __shfl_up(X, 1, 64);
        const float cnext = __shfl(X, 63, 64);   // lane 63 is never in the
                                                 // first partial segment -> X
                                                 // is its true pixel syn
        float cin = (j >= 1 && lane >= 1) ? cinw : 0.0f;
        if (j0 > 0 && lane < C4 - j0)            // first partial segment
            cin = fmaf(carry, pw, cin);

        float st, d;
        st = fmaf(cin, dd1, s0); d = fmaf(st, -inv_tau, oc.x); acc = fmaf(d, d, acc);
        st = fmaf(cin, dd2, s1); d = fmaf(st, -inv_tau, oc.y); acc = fmaf(d, d, acc);
        st = fmaf(cin, dd3, s2); d = fmaf(st, -inv_tau, oc.z); acc = fmaf(d, d, acc);
        st = fmaf(cin, dd4, s3); d = fmaf(st, -inv_tau, oc.w); acc = fmaf(d, d, acc);

        carry = cnext;
        j0 += 64 % C4;                // +14
        if (j0 >= C4) j0 -= C4;
        tc = tn; oc = on;
    }

    // wave-64 shuffle reduction
    #pragma unroll
    for (int off = 32; off > 0; off >>= 1)
        acc += __shfl_down(acc, off, 64);

    __shared__ float wave_sums[4];
    const int wid = threadIdx.x >> 6;
    if (lane == 0) wave_sums[wid] = acc;
    __syncthreads();

    if (threadIdx.x == 0) {
        const float s = wave_sums[0] + wave_sums[1] + wave_sums[2] + wave_sums[3];
        atomicAdd(out, 0.5f * s);
    }
}

extern "C" void kernel_launch(void* const* d_in, const int* in_sizes, int n_in,
                              void* d_out, int out_size, void* d_ws, size_t ws_size,
                              hipStream_t stream) {
    const float* outs = (const float*)d_in[0];   // outputs [B,C,H,W,T]
    const float* tgt  = (const float*)d_in[1];   // target  [B,C,H,W,T]
    const int* tau_p  = (const int*)d_in[3];     // tau_s
    float* out        = (float*)d_out;

    const int n_pixels = in_sizes[0] / T;        // 524288
    const int n_waves  = n_pixels / PPW;         // 8192
    const int block    = 256;
    const int grid     = n_waves * 64 / block;   // 2048 -> 32 waves/CU

    // d_out is poisoned to 0xAA before every call — zero it (graph-capturable).
    hipMemsetAsync(out, 0, sizeof(float), stream);

    spike_loss_kernel<<<grid, block, 0, stream>>>(
        (const float4*)tgt, (const float4*)outs, tau_p, out);
}